// Round 1
// baseline (528.560 us; speedup 1.0000x reference)
//
#include <hip/hip_runtime.h>
#include <float.h>
#include <math.h>

#define BB 64
#define NNtok 197
#define DD 768
#define HH 12
#define PP 12
#define CC 200
#define NPATCH 196

// ---------------- K0: rnorm of arc_w rows ----------------
__global__ __launch_bounds__(64) void k_wnorm(const float* __restrict__ aw,
                                              float* __restrict__ rn) {
  int c = blockIdx.x, l = threadIdx.x;
  float s = 0.f;
  const float* row = aw + (size_t)c * 1536;
  for (int k = l; k < 1536; k += 64) { float v = row[k]; s += v * v; }
  for (int off = 32; off > 0; off >>= 1) s += __shfl_down(s, off);
  if (l == 0) rn[c] = rsqrtf(s);
}

// ---------------- K1: attn scores + top-12 + gather + LN1 ----------------
__global__ __launch_bounds__(256) void k_select_ln1(
    const float* __restrict__ hidden, const float* __restrict__ attns,
    const float* __restrict__ g, const float* __restrict__ be,
    float* __restrict__ parts) {
  int b = blockIdx.x, t = threadIdx.x;
  __shared__ float sc[NPATCH];
  __shared__ float rv[256];
  __shared__ int ri[256];
  __shared__ int sel[PP];
  __shared__ float red[256], red2[256];

  // scores: mean over heads (/12) then mean over layers (/4), matching ref order
  if (t < NPATCH) {
    float acc = 0.f;
    for (int l = 0; l < 4; l++) {
      float part = 0.f;
      for (int h = 0; h < HH; h++) {
        size_t base = (size_t)((l * BB + b) * HH + h) * ((size_t)NNtok * NNtok);
        part += attns[base + 1 + t];
      }
      acc += part * (1.f / 12.f);
    }
    sc[t] = acc * 0.25f;
  }
  __syncthreads();

  // iterative top-12 (ties -> lower index, matches lax.top_k)
  for (int it = 0; it < PP; ++it) {
    float v = (t < NPATCH) ? sc[t] : -FLT_MAX;
    rv[t] = v; ri[t] = t;
    __syncthreads();
    for (int s = 128; s > 0; s >>= 1) {
      if (t < s) {
        float v2 = rv[t + s]; int i2 = ri[t + s];
        if (v2 > rv[t] || (v2 == rv[t] && i2 < ri[t])) { rv[t] = v2; ri[t] = i2; }
      }
      __syncthreads();
    }
    if (t == 0) { sel[it] = ri[0]; sc[ri[0]] = -FLT_MAX; }
    __syncthreads();
  }

  // gather selected patches + LayerNorm1
  for (int i = 0; i < PP; i++) {
    const float* row = hidden + ((size_t)b * NNtok + 1 + sel[i]) * DD;
    float x0 = row[t], x1 = row[t + 256], x2 = row[t + 512];
    red[t] = x0 + x1 + x2;
    red2[t] = x0 * x0 + x1 * x1 + x2 * x2;
    __syncthreads();
    for (int st = 128; st > 0; st >>= 1) {
      if (t < st) { red[t] += red[t + st]; red2[t] += red2[t + st]; }
      __syncthreads();
    }
    float mean = red[0] * (1.f / DD);
    float var = red2[0] * (1.f / DD) - mean * mean;
    float rstd = rsqrtf(var + 1e-5f);
    float* out = parts + ((size_t)b * PP + i) * DD;
    out[t]       = (x0 - mean) * rstd * g[t]       + be[t];
    out[t + 256] = (x1 - mean) * rstd * g[t + 256] + be[t + 256];
    out[t + 512] = (x2 - mean) * rstd * g[t + 512] + be[t + 512];
    __syncthreads();  // red reuse next iter
  }
}

// ---------------- tiled f32 GEMM: C = A(MxK) @ W(NxK)^T + bias ----------------
template <int RELU>
__global__ __launch_bounds__(256) void k_gemm(
    const float* __restrict__ A, const float* __restrict__ W,
    const float* __restrict__ bias, float* __restrict__ Cd,
    int M, int Nn, int Kk) {
  __shared__ float As[16][68];
  __shared__ float Bs[16][68];
  int t = threadIdx.x;
  int tx = t & 15, ty = t >> 4;
  int mb = blockIdx.y * 64, nb = blockIdx.x * 64;
  int lr = t >> 2;         // 0..63
  int lc = (t & 3) * 4;    // 0,4,8,12
  const float* Ap = A + (size_t)(mb + lr) * Kk + lc;
  const float* Wp = W + (size_t)(nb + lr) * Kk + lc;
  float acc[4][4] = {};
  for (int k0 = 0; k0 < Kk; k0 += 16) {
    float4 av = *(const float4*)(Ap + k0);
    float4 wv = *(const float4*)(Wp + k0);
    As[lc + 0][lr] = av.x; As[lc + 1][lr] = av.y;
    As[lc + 2][lr] = av.z; As[lc + 3][lr] = av.w;
    Bs[lc + 0][lr] = wv.x; Bs[lc + 1][lr] = wv.y;
    Bs[lc + 2][lr] = wv.z; Bs[lc + 3][lr] = wv.w;
    __syncthreads();
#pragma unroll
    for (int k = 0; k < 16; k++) {
      float4 a4 = *(const float4*)&As[k][ty * 4];
      float4 b4 = *(const float4*)&Bs[k][tx * 4];
      float am[4] = {a4.x, a4.y, a4.z, a4.w};
      float bm[4] = {b4.x, b4.y, b4.z, b4.w};
#pragma unroll
      for (int i = 0; i < 4; i++)
#pragma unroll
        for (int j = 0; j < 4; j++) acc[i][j] += am[i] * bm[j];
    }
    __syncthreads();
  }
  float4 bb = *(const float4*)&bias[nb + tx * 4];
  float bv[4] = {bb.x, bb.y, bb.z, bb.w};
#pragma unroll
  for (int i = 0; i < 4; i++) {
    float4 o;
    o.x = acc[i][0] + bv[0]; o.y = acc[i][1] + bv[1];
    o.z = acc[i][2] + bv[2]; o.w = acc[i][3] + bv[3];
    if (RELU) {
      o.x = fmaxf(o.x, 0.f); o.y = fmaxf(o.y, 0.f);
      o.z = fmaxf(o.z, 0.f); o.w = fmaxf(o.w, 0.f);
    }
    *(float4*)(Cd + (size_t)(mb + ty * 4 + i) * Nn + nb + tx * 4) = o;
  }
}

// ---------------- K3: tiny attention per (b,h) ----------------
__global__ __launch_bounds__(256) void k_attn(const float* __restrict__ qkv,
                                              float* __restrict__ o) {
  int bh = blockIdx.x;
  int b = bh / HH, h = bh % HH;
  __shared__ float qs[12][64], ks[12][64], vs[12][64], sm[12][12];
  int t = threadIdx.x;
  for (int u = t; u < 768; u += 256) {
    int p = u >> 6, d = u & 63;
    size_t base = ((size_t)(b * PP + p)) * 2304 + h * 64 + d;
    qs[p][d] = qkv[base];
    ks[p][d] = qkv[base + 768];
    vs[p][d] = qkv[base + 1536];
  }
  __syncthreads();
  if (t < 144) {
    int i = t / 12, j = t % 12;
    float s = 0.f;
#pragma unroll
    for (int d = 0; d < 64; d++) s += qs[i][d] * ks[j][d];
    sm[i][j] = s * 0.125f;  // 1/sqrt(64)
  }
  __syncthreads();
  if (t < 12) {
    float m = -FLT_MAX;
    for (int j = 0; j < 12; j++) m = fmaxf(m, sm[t][j]);
    float e[12], sum = 0.f;
    for (int j = 0; j < 12; j++) { e[j] = expf(sm[t][j] - m); sum += e[j]; }
    float inv = 1.f / sum;
    for (int j = 0; j < 12; j++) sm[t][j] = e[j] * inv;
  }
  __syncthreads();
  for (int u = t; u < 768; u += 256) {
    int i = u >> 6, d = u & 63;
    float s = 0.f;
#pragma unroll
    for (int j = 0; j < 12; j++) s += sm[i][j] * vs[j][d];
    o[((size_t)(b * PP + i)) * DD + h * 64 + d] = s;
  }
}

// ---------------- K5: LN2 (in-place) + pooling logit per row ----------------
__global__ __launch_bounds__(256) void k_ln2_pool(
    float* __restrict__ x, const float* __restrict__ g,
    const float* __restrict__ be, const float* __restrict__ wp,
    const float* __restrict__ bp, float* __restrict__ raww) {
  int r = blockIdx.x, t = threadIdx.x;
  __shared__ float red[256], red2[256];
  float* row = x + (size_t)r * DD;
  float x0 = row[t], x1 = row[t + 256], x2 = row[t + 512];
  red[t] = x0 + x1 + x2;
  red2[t] = x0 * x0 + x1 * x1 + x2 * x2;
  __syncthreads();
  for (int st = 128; st > 0; st >>= 1) {
    if (t < st) { red[t] += red[t + st]; red2[t] += red2[t + st]; }
    __syncthreads();
  }
  float mean = red[0] * (1.f / DD);
  float var = red2[0] * (1.f / DD) - mean * mean;
  float rstd = rsqrtf(var + 1e-5f);
  float y0 = (x0 - mean) * rstd * g[t] + be[t];
  float y1 = (x1 - mean) * rstd * g[t + 256] + be[t + 256];
  float y2 = (x2 - mean) * rstd * g[t + 512] + be[t + 512];
  row[t] = y0; row[t + 256] = y1; row[t + 512] = y2;
  __syncthreads();
  red[t] = y0 * wp[t] + y1 * wp[t + 256] + y2 * wp[t + 512];
  __syncthreads();
  for (int st = 128; st > 0; st >>= 1) {
    if (t < st) red[t] += red[t + st];
    __syncthreads();
  }
  if (t == 0) raww[r] = red[0] + bp[0];
}

// ---------------- K6: pool softmax + weighted sum ----------------
__global__ __launch_bounds__(256) void k_pool(
    const float* __restrict__ aout, const float* __restrict__ raww,
    const float* __restrict__ ptemp, float* __restrict__ pf) {
  int b = blockIdx.x, t = threadIdx.x;
  __shared__ float w[12];
  if (t == 0) {
    float temp = fmaxf(ptemp[0], 0.3f), inv = 1.f / temp;
    float z[12], m = -FLT_MAX;
    for (int p = 0; p < 12; p++) { z[p] = raww[b * 12 + p] * inv; m = fmaxf(m, z[p]); }
    float s = 0.f;
    for (int p = 0; p < 12; p++) { z[p] = expf(z[p] - m); s += z[p]; }
    float is = 1.f / s;
    for (int p = 0; p < 12; p++) w[p] = z[p] * is;
  }
  __syncthreads();
  for (int d = t; d < DD; d += 256) {
    float s = 0.f;
#pragma unroll
    for (int p = 0; p < 12; p++) s += aout[((size_t)(b * 12 + p)) * DD + d] * w[p];
    pf[(size_t)b * DD + d] = s;
  }
}

// ---------------- K8: fusion + ArcFace logits ----------------
__global__ __launch_bounds__(256) void k_arc(
    const float* __restrict__ hidden, const float* __restrict__ pmlp,
    const float* __restrict__ aw, const float* __restrict__ rn,
    const int* __restrict__ labels, float* __restrict__ out) {
  int b = blockIdx.x, t = threadIdx.x;
  __shared__ float fus[1536];
  __shared__ float red[256];
  __shared__ float rnf;
  for (int u = t; u < 768; u += 256) {
    fus[u] = hidden[((size_t)b * NNtok) * DD + u];  // cls token
    fus[768 + u] = pmlp[(size_t)b * DD + u];
  }
  __syncthreads();
  float s = 0.f;
  for (int u = t; u < 1536; u += 256) s += fus[u] * fus[u];
  red[t] = s;
  __syncthreads();
  for (int st = 128; st > 0; st >>= 1) {
    if (t < st) red[t] += red[t + st];
    __syncthreads();
  }
  if (t == 0) rnf = rsqrtf(red[0]);
  __syncthreads();
  int lab = labels[b];
  int wv = t >> 6, ln = t & 63;
  const float cos_m = 0.8775825618903728f, sin_m = 0.479425538604203f;
  const float th = -0.8775825618903728f, mm = 0.2397127693021015f;
  for (int c = wv; c < CC; c += 4) {
    float acc = 0.f;
    const float* awr = aw + (size_t)c * 1536;
    for (int k = ln; k < 1536; k += 64) acc += fus[k] * awr[k];
    for (int off = 32; off > 0; off >>= 1) acc += __shfl_down(acc, off);
    if (ln == 0) {
      float cosv = acc * rnf * rn[c];
      float s2 = 1.f - cosv * cosv;
      s2 = fminf(fmaxf(s2, 0.f), 1.f);
      float sinv = sqrtf(s2);
      float phi = cosv * cos_m - sinv * sin_m;
      phi = (cosv > th) ? phi : (cosv - mm);
      out[(size_t)b * CC + c] = ((c == lab) ? phi : cosv) * 30.f;
    }
  }
}

extern "C" void kernel_launch(void* const* d_in, const int* in_sizes, int n_in,
                              void* d_out, int out_size, void* d_ws, size_t ws_size,
                              hipStream_t stream) {
  const float* hidden = (const float*)d_in[0];
  const float* attns  = (const float*)d_in[1];
  const int*   labels = (const int*)d_in[2];
  const float* ln1_g  = (const float*)d_in[3];
  const float* ln1_b  = (const float*)d_in[4];
  const float* w_in   = (const float*)d_in[5];
  const float* b_in   = (const float*)d_in[6];
  const float* w_out  = (const float*)d_in[7];
  const float* b_out  = (const float*)d_in[8];
  const float* ln2_g  = (const float*)d_in[9];
  const float* ln2_b  = (const float*)d_in[10];
  const float* w_pool = (const float*)d_in[11];
  const float* b_pool = (const float*)d_in[12];
  const float* ptemp  = (const float*)d_in[13];
  const float* w_mlp  = (const float*)d_in[14];
  const float* b_mlp  = (const float*)d_in[15];
  const float* arc_w  = (const float*)d_in[16];
  float* outp = (float*)d_out;

  float* F = (float*)d_ws;
  float* wnr   = F + 768;                 // 200
  float* parts = F + 1024;                // 768*768 (also reused as o-buffer)
  float* qkv   = parts + 589824;          // 768*2304 (also reused as attn_out)
  float* raww  = qkv + 1769472;           // 768
  float* pfeat = raww + 768;              // 64*768
  float* pmlp  = pfeat + 49152;           // 64*768
  // aliases (lifetimes disjoint):
  float* obuf = parts;  // parts dead after qkv GEMM; o written by k_attn
  float* aout = qkv;    // qkv dead after k_attn; attn_out written by w_out GEMM

  k_wnorm<<<200, 64, 0, stream>>>(arc_w, wnr);
  k_select_ln1<<<BB, 256, 0, stream>>>(hidden, attns, ln1_g, ln1_b, parts);
  k_gemm<0><<<dim3(2304 / 64, 768 / 64), 256, 0, stream>>>(parts, w_in, b_in, qkv, 768, 2304, 768);
  k_attn<<<BB * HH, 256, 0, stream>>>(qkv, obuf);
  k_gemm<0><<<dim3(768 / 64, 768 / 64), 256, 0, stream>>>(obuf, w_out, b_out, aout, 768, 768, 768);
  k_ln2_pool<<<BB * PP, 256, 0, stream>>>(aout, ln2_g, ln2_b, w_pool, b_pool, raww);
  k_pool<<<BB, 256, 0, stream>>>(aout, raww, ptemp, pfeat);
  k_gemm<1><<<dim3(768 / 64, 1), 256, 0, stream>>>(pfeat, w_mlp, b_mlp, pmlp, 64, 768, 768);
  k_arc<<<BB, 256, 0, stream>>>(hidden, pmlp, arc_w, wnr, labels, outp);
}

// Round 2
// 192.119 us; speedup vs baseline: 2.7512x; 2.7512x over previous
//
#include <hip/hip_runtime.h>
#include <float.h>
#include <math.h>

#define BB 64
#define NNtok 197
#define DD 768
#define HH 12
#define PP 12
#define CC 200
#define NPATCH 196

// ---------------- K0: rnorm of arc_w rows ----------------
__global__ __launch_bounds__(64) void k_wnorm(const float* __restrict__ aw,
                                              float* __restrict__ rn) {
  int c = blockIdx.x, l = threadIdx.x;
  float s = 0.f;
  const float* row = aw + (size_t)c * 1536;
  for (int k = l; k < 1536; k += 64) { float v = row[k]; s += v * v; }
  for (int off = 32; off > 0; off >>= 1) s += __shfl_down(s, off);
  if (l == 0) rn[c] = rsqrtf(s);
}

// ---------------- K1: attn scores + top-12 + gather + LN1 ----------------
__global__ __launch_bounds__(256) void k_select_ln1(
    const float* __restrict__ hidden, const float* __restrict__ attns,
    const float* __restrict__ g, const float* __restrict__ be,
    float* __restrict__ parts) {
  int b = blockIdx.x, t = threadIdx.x;
  __shared__ float sc[NPATCH];
  __shared__ float rv[256];
  __shared__ int ri[256];
  __shared__ int sel[PP];
  __shared__ float red[256], red2[256];

  // scores: mean over heads (/12) then mean over layers (/4), matching ref order
  if (t < NPATCH) {
    float acc = 0.f;
    for (int l = 0; l < 4; l++) {
      float part = 0.f;
      for (int h = 0; h < HH; h++) {
        size_t base = (size_t)((l * BB + b) * HH + h) * ((size_t)NNtok * NNtok);
        part += attns[base + 1 + t];
      }
      acc += part * (1.f / 12.f);
    }
    sc[t] = acc * 0.25f;
  }
  __syncthreads();

  // iterative top-12 (ties -> lower index, matches lax.top_k)
  for (int it = 0; it < PP; ++it) {
    float v = (t < NPATCH) ? sc[t] : -FLT_MAX;
    rv[t] = v; ri[t] = t;
    __syncthreads();
    for (int s = 128; s > 0; s >>= 1) {
      if (t < s) {
        float v2 = rv[t + s]; int i2 = ri[t + s];
        if (v2 > rv[t] || (v2 == rv[t] && i2 < ri[t])) { rv[t] = v2; ri[t] = i2; }
      }
      __syncthreads();
    }
    if (t == 0) { sel[it] = ri[0]; sc[ri[0]] = -FLT_MAX; }
    __syncthreads();
  }

  // gather selected patches + LayerNorm1
  for (int i = 0; i < PP; i++) {
    const float* row = hidden + ((size_t)b * NNtok + 1 + sel[i]) * DD;
    float x0 = row[t], x1 = row[t + 256], x2 = row[t + 512];
    red[t] = x0 + x1 + x2;
    red2[t] = x0 * x0 + x1 * x1 + x2 * x2;
    __syncthreads();
    for (int st = 128; st > 0; st >>= 1) {
      if (t < st) { red[t] += red[t + st]; red2[t] += red2[t + st]; }
      __syncthreads();
    }
    float mean = red[0] * (1.f / DD);
    float var = red2[0] * (1.f / DD) - mean * mean;
    float rstd = rsqrtf(var + 1e-5f);
    float* out = parts + ((size_t)b * PP + i) * DD;
    out[t]       = (x0 - mean) * rstd * g[t]       + be[t];
    out[t + 256] = (x1 - mean) * rstd * g[t + 256] + be[t + 256];
    out[t + 512] = (x2 - mean) * rstd * g[t + 512] + be[t + 512];
    __syncthreads();  // red reuse next iter
  }
}

// ---------------- tiled f32 GEMM: C = A(MxK) @ W(NxK)^T + bias ----------------
template <int RELU>
__global__ __launch_bounds__(256) void k_gemm(
    const float* __restrict__ A, const float* __restrict__ W,
    const float* __restrict__ bias, float* __restrict__ Cd,
    int M, int Nn, int Kk) {
  __shared__ float As[16][68];
  __shared__ float Bs[16][68];
  int t = threadIdx.x;
  int tx = t & 15, ty = t >> 4;
  int mb = blockIdx.y * 64, nb = blockIdx.x * 64;
  int lr = t >> 2;         // 0..63
  int lc = (t & 3) * 4;    // 0,4,8,12
  const float* Ap = A + (size_t)(mb + lr) * Kk + lc;
  const float* Wp = W + (size_t)(nb + lr) * Kk + lc;
  float acc[4][4] = {};
  for (int k0 = 0; k0 < Kk; k0 += 16) {
    float4 av = *(const float4*)(Ap + k0);
    float4 wv = *(const float4*)(Wp + k0);
    As[lc + 0][lr] = av.x; As[lc + 1][lr] = av.y;
    As[lc + 2][lr] = av.z; As[lc + 3][lr] = av.w;
    Bs[lc + 0][lr] = wv.x; Bs[lc + 1][lr] = wv.y;
    Bs[lc + 2][lr] = wv.z; Bs[lc + 3][lr] = wv.w;
    __syncthreads();
#pragma unroll
    for (int k = 0; k < 16; k++) {
      float4 a4 = *(const float4*)&As[k][ty * 4];
      float4 b4 = *(const float4*)&Bs[k][tx * 4];
      float am[4] = {a4.x, a4.y, a4.z, a4.w};
      float bm[4] = {b4.x, b4.y, b4.z, b4.w};
#pragma unroll
      for (int i = 0; i < 4; i++)
#pragma unroll
        for (int j = 0; j < 4; j++) acc[i][j] += am[i] * bm[j];
    }
    __syncthreads();
  }
  float4 bb = *(const float4*)&bias[nb + tx * 4];
  float bv[4] = {bb.x, bb.y, bb.z, bb.w};
#pragma unroll
  for (int i = 0; i < 4; i++) {
    float4 o;
    o.x = acc[i][0] + bv[0]; o.y = acc[i][1] + bv[1];
    o.z = acc[i][2] + bv[2]; o.w = acc[i][3] + bv[3];
    if (RELU) {
      o.x = fmaxf(o.x, 0.f); o.y = fmaxf(o.y, 0.f);
      o.z = fmaxf(o.z, 0.f); o.w = fmaxf(o.w, 0.f);
    }
    *(float4*)(Cd + (size_t)(mb + ty * 4 + i) * Nn + nb + tx * 4) = o;
  }
}

// ---------------- K3: tiny attention per (b,h) ----------------
__global__ __launch_bounds__(256) void k_attn(const float* __restrict__ qkv,
                                              float* __restrict__ o) {
  int bh = blockIdx.x;
  int b = bh / HH, h = bh % HH;
  __shared__ float qs[12][64], ks[12][64], vs[12][64], sm[12][12];
  int t = threadIdx.x;
  for (int u = t; u < 768; u += 256) {
    int p = u >> 6, d = u & 63;
    size_t base = ((size_t)(b * PP + p)) * 2304 + h * 64 + d;
    qs[p][d] = qkv[base];
    ks[p][d] = qkv[base + 768];
    vs[p][d] = qkv[base + 1536];
  }
  __syncthreads();
  if (t < 144) {
    int i = t / 12, j = t % 12;
    float s = 0.f;
#pragma unroll
    for (int d = 0; d < 64; d++) s += qs[i][d] * ks[j][d];
    sm[i][j] = s * 0.125f;  // 1/sqrt(64)
  }
  __syncthreads();
  if (t < 12) {
    float m = -FLT_MAX;
    for (int j = 0; j < 12; j++) m = fmaxf(m, sm[t][j]);
    float e[12], sum = 0.f;
    for (int j = 0; j < 12; j++) { e[j] = expf(sm[t][j] - m); sum += e[j]; }
    float inv = 1.f / sum;
    for (int j = 0; j < 12; j++) sm[t][j] = e[j] * inv;
  }
  __syncthreads();
  for (int u = t; u < 768; u += 256) {
    int i = u >> 6, d = u & 63;
    float s = 0.f;
#pragma unroll
    for (int j = 0; j < 12; j++) s += sm[i][j] * vs[j][d];
    o[((size_t)(b * PP + i)) * DD + h * 64 + d] = s;
  }
}

// ---------------- K5: LN2 (in-place) + pooling logit per row ----------------
__global__ __launch_bounds__(256) void k_ln2_pool(
    float* __restrict__ x, const float* __restrict__ g,
    const float* __restrict__ be, const float* __restrict__ wp,
    const float* __restrict__ bp, float* __restrict__ raww) {
  int r = blockIdx.x, t = threadIdx.x;
  __shared__ float red[256], red2[256];
  float* row = x + (size_t)r * DD;
  float x0 = row[t], x1 = row[t + 256], x2 = row[t + 512];
  red[t] = x0 + x1 + x2;
  red2[t] = x0 * x0 + x1 * x1 + x2 * x2;
  __syncthreads();
  for (int st = 128; st > 0; st >>= 1) {
    if (t < st) { red[t] += red[t + st]; red2[t] += red2[t + st]; }
    __syncthreads();
  }
  float mean = red[0] * (1.f / DD);
  float var = red2[0] * (1.f / DD) - mean * mean;
  float rstd = rsqrtf(var + 1e-5f);
  float y0 = (x0 - mean) * rstd * g[t] + be[t];
  float y1 = (x1 - mean) * rstd * g[t + 256] + be[t + 256];
  float y2 = (x2 - mean) * rstd * g[t + 512] + be[t + 512];
  row[t] = y0; row[t + 256] = y1; row[t + 512] = y2;
  __syncthreads();
  red[t] = y0 * wp[t] + y1 * wp[t + 256] + y2 * wp[t + 512];
  __syncthreads();
  for (int st = 128; st > 0; st >>= 1) {
    if (t < st) red[t] += red[t + st];
    __syncthreads();
  }
  if (t == 0) raww[r] = red[0] + bp[0];
}

// ---------------- K6: pool softmax + weighted sum ----------------
__global__ __launch_bounds__(256) void k_pool(
    const float* __restrict__ aout, const float* __restrict__ raww,
    const float* __restrict__ ptemp, float* __restrict__ pf) {
  int b = blockIdx.x, t = threadIdx.x;
  __shared__ float w[12];
  if (t == 0) {
    float temp = fmaxf(ptemp[0], 0.3f), inv = 1.f / temp;
    float z[12], m = -FLT_MAX;
    for (int p = 0; p < 12; p++) { z[p] = raww[b * 12 + p] * inv; m = fmaxf(m, z[p]); }
    float s = 0.f;
    for (int p = 0; p < 12; p++) { z[p] = expf(z[p] - m); s += z[p]; }
    float is = 1.f / s;
    for (int p = 0; p < 12; p++) w[p] = z[p] * is;
  }
  __syncthreads();
  for (int d = t; d < DD; d += 256) {
    float s = 0.f;
#pragma unroll
    for (int p = 0; p < 12; p++) s += aout[((size_t)(b * 12 + p)) * DD + d] * w[p];
    pf[(size_t)b * DD + d] = s;
  }
}

// ---------------- K8a: fusion vector, normalized, -> ws ----------------
__global__ __launch_bounds__(256) void k_fusion(
    const float* __restrict__ hidden, const float* __restrict__ pmlp,
    float* __restrict__ fus_n) {
  int b = blockIdx.x, t = threadIdx.x;
  __shared__ float red[256];
  __shared__ float rnf;
  float v[6];
#pragma unroll
  for (int j = 0; j < 6; j++) {
    int u = t + j * 256;
    v[j] = (u < 768) ? hidden[((size_t)b * NNtok) * DD + u]
                     : pmlp[(size_t)b * DD + (u - 768)];
  }
  float s = 0.f;
#pragma unroll
  for (int j = 0; j < 6; j++) s += v[j] * v[j];
  red[t] = s;
  __syncthreads();
  for (int st = 128; st > 0; st >>= 1) {
    if (t < st) red[t] += red[t + st];
    __syncthreads();
  }
  if (t == 0) rnf = rsqrtf(red[0]);
  __syncthreads();
  float r = rnf;
#pragma unroll
  for (int j = 0; j < 6; j++) fus_n[(size_t)b * 1536 + t + j * 256] = v[j] * r;
}

// ---------------- K8b: ArcFace logits, 8 classes/block ----------------
__global__ __launch_bounds__(256) void k_arc2(
    const float* __restrict__ fus_n, const float* __restrict__ aw,
    const float* __restrict__ rn, const int* __restrict__ labels,
    float* __restrict__ out) {
  int cbase = blockIdx.x * 8, b = blockIdx.y, t = threadIdx.x;
  __shared__ float4 fs[384];
  for (int u = t; u < 384; u += 256)
    fs[u] = ((const float4*)(fus_n + (size_t)b * 1536))[u];
  __syncthreads();
  int wv = t >> 6, ln = t & 63;
  int lab = labels[b];
  const float cos_m = 0.8775825618903728f, sin_m = 0.479425538604203f;
  const float th = -0.8775825618903728f, mm = 0.2397127693021015f;
#pragma unroll
  for (int ci = 0; ci < 2; ci++) {
    int c = cbase + wv + ci * 4;
    const float4* awr = (const float4*)(aw + (size_t)c * 1536);
    float acc = 0.f;
#pragma unroll
    for (int k = 0; k < 6; k++) {
      float4 a = fs[ln + k * 64];
      float4 w = awr[ln + k * 64];
      acc += a.x * w.x + a.y * w.y + a.z * w.z + a.w * w.w;
    }
    for (int off = 32; off > 0; off >>= 1) acc += __shfl_down(acc, off);
    if (ln == 0) {
      float cosv = acc * rn[c];
      float s2 = 1.f - cosv * cosv;
      s2 = fminf(fmaxf(s2, 0.f), 1.f);
      float sinv = sqrtf(s2);
      float phi = cosv * cos_m - sinv * sin_m;
      phi = (cosv > th) ? phi : (cosv - mm);
      out[(size_t)b * CC + c] = ((c == lab) ? phi : cosv) * 30.f;
    }
  }
}

extern "C" void kernel_launch(void* const* d_in, const int* in_sizes, int n_in,
                              void* d_out, int out_size, void* d_ws, size_t ws_size,
                              hipStream_t stream) {
  const float* hidden = (const float*)d_in[0];
  const float* attns  = (const float*)d_in[1];
  const int*   labels = (const int*)d_in[2];
  const float* ln1_g  = (const float*)d_in[3];
  const float* ln1_b  = (const float*)d_in[4];
  const float* w_in   = (const float*)d_in[5];
  const float* b_in   = (const float*)d_in[6];
  const float* w_out  = (const float*)d_in[7];
  const float* b_out  = (const float*)d_in[8];
  const float* ln2_g  = (const float*)d_in[9];
  const float* ln2_b  = (const float*)d_in[10];
  const float* w_pool = (const float*)d_in[11];
  const float* b_pool = (const float*)d_in[12];
  const float* ptemp  = (const float*)d_in[13];
  const float* w_mlp  = (const float*)d_in[14];
  const float* b_mlp  = (const float*)d_in[15];
  const float* arc_w  = (const float*)d_in[16];
  float* outp = (float*)d_out;

  float* F = (float*)d_ws;
  float* wnr   = F + 768;                 // 200
  float* parts = F + 1024;                // 768*768 (also reused as o-buffer)
  float* qkv   = parts + 589824;          // 768*2304 (also reused as attn_out)
  float* raww  = qkv + 1769472;           // 768
  float* pfeat = raww + 768;              // 64*768
  float* pmlp  = pfeat + 49152;           // 64*768
  float* fus_n = pmlp + 49152;            // 64*1536
  // aliases (lifetimes disjoint):
  float* obuf = parts;  // parts dead after qkv GEMM; o written by k_attn
  float* aout = qkv;    // qkv dead after k_attn; attn_out written by w_out GEMM

  k_wnorm<<<200, 64, 0, stream>>>(arc_w, wnr);
  k_select_ln1<<<BB, 256, 0, stream>>>(hidden, attns, ln1_g, ln1_b, parts);
  k_gemm<0><<<dim3(2304 / 64, 768 / 64), 256, 0, stream>>>(parts, w_in, b_in, qkv, 768, 2304, 768);
  k_attn<<<BB * HH, 256, 0, stream>>>(qkv, obuf);
  k_gemm<0><<<dim3(768 / 64, 768 / 64), 256, 0, stream>>>(obuf, w_out, b_out, aout, 768, 768, 768);
  k_ln2_pool<<<BB * PP, 256, 0, stream>>>(aout, ln2_g, ln2_b, w_pool, b_pool, raww);
  k_pool<<<BB, 256, 0, stream>>>(aout, raww, ptemp, pfeat);
  k_gemm<1><<<dim3(768 / 64, 1), 256, 0, stream>>>(pfeat, w_mlp, b_mlp, pmlp, 64, 768, 768);
  k_fusion<<<BB, 256, 0, stream>>>(hidden, pmlp, fus_n);
  k_arc2<<<dim3(25, BB), 256, 0, stream>>>(fus_n, arc_w, wnr, labels, outp);
}

// Round 3
// 113.947 us; speedup vs baseline: 4.6386x; 1.6860x over previous
//
#include <hip/hip_runtime.h>
#include <hip/hip_bf16.h>
#include <float.h>
#include <math.h>

#define BB 64
#define NNtok 197
#define DD 768
#define HH 12
#define PP 12
#define CC 200
#define NPATCH 196

typedef short bf16x8 __attribute__((ext_vector_type(8)));
typedef float f32x4 __attribute__((ext_vector_type(4)));

__device__ __forceinline__ unsigned short bf16_bits(float x) {
  __hip_bfloat16 h = __float2bfloat16(x);
  return *reinterpret_cast<unsigned short*>(&h);
}
__device__ __forceinline__ float bf16_val(const __hip_bfloat16* p) {
  return __bfloat162float(*p);
}

// ---------------- K0: rnorm of arc_w rows ----------------
__global__ __launch_bounds__(64) void k_wnorm(const float* __restrict__ aw,
                                              float* __restrict__ rn) {
  int c = blockIdx.x, l = threadIdx.x;
  float s = 0.f;
  const float* row = aw + (size_t)c * 1536;
  for (int k = l; k < 1536; k += 64) { float v = row[k]; s += v * v; }
  for (int off = 32; off > 0; off >>= 1) s += __shfl_down(s, off);
  if (l == 0) rn[c] = rsqrtf(s);
}

// ---------------- cast 3 weight matrices to bf16 (float4 granularity) -------
__global__ __launch_bounds__(256) void k_cast3(
    const float* __restrict__ w1, const float* __restrict__ w2,
    const float* __restrict__ w3, __hip_bfloat16* __restrict__ o1,
    __hip_bfloat16* __restrict__ o2, __hip_bfloat16* __restrict__ o3) {
  int i = blockIdx.x * 256 + threadIdx.x;  // float4 index; total 737280
  const float* src; __hip_bfloat16* dst; int off;
  if (i < 442368) { src = w1; dst = o1; off = i; }
  else if (i < 589824) { src = w2; dst = o2; off = i - 442368; }
  else { src = w3; dst = o3; off = i - 589824; }
  float4 v = ((const float4*)src)[off];
  union { unsigned short u[4]; ushort4 v4; } p;
  p.u[0] = bf16_bits(v.x); p.u[1] = bf16_bits(v.y);
  p.u[2] = bf16_bits(v.z); p.u[3] = bf16_bits(v.w);
  ((ushort4*)dst)[off] = p.v4;
}

// ---------------- K1a: attn scores + single-wave top-12 ----------------
__global__ __launch_bounds__(256) void k_select(
    const float* __restrict__ attns, int* __restrict__ sel_g) {
  int b = blockIdx.x, t = threadIdx.x;
  __shared__ float sc[256];
  float acc = -FLT_MAX;
  if (t < NPATCH) {
    acc = 0.f;
#pragma unroll
    for (int l = 0; l < 4; l++) {
      float part = 0.f;
#pragma unroll
      for (int h = 0; h < HH; h++) {
        size_t base = (size_t)((l * BB + b) * HH + h) * ((size_t)NNtok * NNtok);
        part += attns[base + 1 + t];
      }
      acc += part * (1.f / 12.f);
    }
    acc *= 0.25f;
  }
  sc[t] = acc;
  __syncthreads();
  if (t < 64) {
    float v[4]; int idx[4];
#pragma unroll
    for (int j = 0; j < 4; j++) { idx[j] = t + j * 64; v[j] = sc[idx[j]]; }
    for (int it = 0; it < PP; ++it) {
      float bv = v[0]; int bi = idx[0];
#pragma unroll
      for (int j = 1; j < 4; j++)
        if (v[j] > bv || (v[j] == bv && idx[j] < bi)) { bv = v[j]; bi = idx[j]; }
      float cv = bv; int ci = bi;
#pragma unroll
      for (int off = 32; off > 0; off >>= 1) {
        float ov = __shfl_xor(cv, off); int oi = __shfl_xor(ci, off);
        if (ov > cv || (ov == cv && oi < ci)) { cv = ov; ci = oi; }
      }
      if (t == 0) sel_g[b * PP + it] = ci;
#pragma unroll
      for (int j = 0; j < 4; j++)
        if (idx[j] == ci) v[j] = -FLT_MAX;
    }
  }
}

// ---------------- K1b: gather + LN1 -> bf16 parts (one block per (b,part)) --
__global__ __launch_bounds__(256) void k_gather_ln1(
    const float* __restrict__ hidden, const int* __restrict__ sel_g,
    const float* __restrict__ g, const float* __restrict__ be,
    __hip_bfloat16* __restrict__ parts) {
  int blk = blockIdx.x, b = blk / PP, i = blk % PP;
  int t = threadIdx.x;
  int selv = sel_g[b * PP + i];
  const float* row = hidden + ((size_t)b * NNtok + 1 + selv) * DD;
  float x0 = row[t], x1 = row[t + 256], x2 = row[t + 512];
  float s1 = x0 + x1 + x2;
  float s2 = x0 * x0 + x1 * x1 + x2 * x2;
  for (int off = 32; off > 0; off >>= 1) {
    s1 += __shfl_down(s1, off);
    s2 += __shfl_down(s2, off);
  }
  __shared__ float a1[4], a2[4];
  __shared__ float mean_s, rstd_s;
  if ((t & 63) == 0) { a1[t >> 6] = s1; a2[t >> 6] = s2; }
  __syncthreads();
  if (t == 0) {
    float m = (a1[0] + a1[1] + a1[2] + a1[3]) * (1.f / DD);
    float v = (a2[0] + a2[1] + a2[2] + a2[3]) * (1.f / DD) - m * m;
    mean_s = m; rstd_s = rsqrtf(v + 1e-5f);
  }
  __syncthreads();
  float m = mean_s, r = rstd_s;
  __hip_bfloat16* out = parts + ((size_t)b * PP + i) * DD;
  out[t]       = __float2bfloat16((x0 - m) * r * g[t]       + be[t]);
  out[t + 256] = __float2bfloat16((x1 - m) * r * g[t + 256] + be[t + 256]);
  out[t + 512] = __float2bfloat16((x2 - m) * r * g[t + 512] + be[t + 512]);
}

// ---------------- MFMA GEMM: C = A(MxK) @ W(NxK)^T + bias -------------------
// wave tile 64x64 (4x4 of 16x16x32 frags), direct-from-global fragment loads.
template <int WGM, int WGN, int RELU, int OUTBF>
__global__ __launch_bounds__(WGM * WGN * 64) void k_gemm_bf(
    const __hip_bfloat16* __restrict__ A, const __hip_bfloat16* __restrict__ W,
    const float* __restrict__ bias, void* __restrict__ Cd, int Nn, int Kk) {
  int t = threadIdx.x;
  int wave = t >> 6, lane = t & 63;
  int wm = wave / WGN, wn = wave % WGN;
  int row0 = blockIdx.y * (WGM * 64) + wm * 64;
  int col0 = blockIdx.x * (WGN * 64) + wn * 64;
  int lr = lane & 15;   // row (A) / col (W) within 16
  int kg = lane >> 4;   // k-group of 8
  f32x4 acc[4][4];
#pragma unroll
  for (int i = 0; i < 4; i++)
#pragma unroll
    for (int j = 0; j < 4; j++) {
      acc[i][j][0] = 0.f; acc[i][j][1] = 0.f;
      acc[i][j][2] = 0.f; acc[i][j][3] = 0.f;
    }
  const __hip_bfloat16* Ab = A + (size_t)(row0 + lr) * Kk + kg * 8;
  const __hip_bfloat16* Wb = W + (size_t)(col0 + lr) * Kk + kg * 8;
  for (int k0 = 0; k0 < Kk; k0 += 32) {
    bf16x8 af[4], wf[4];
#pragma unroll
    for (int i = 0; i < 4; i++) {
      af[i] = *(const bf16x8*)(Ab + (size_t)i * 16 * Kk + k0);
      wf[i] = *(const bf16x8*)(Wb + (size_t)i * 16 * Kk + k0);
    }
#pragma unroll
    for (int i = 0; i < 4; i++)
#pragma unroll
      for (int j = 0; j < 4; j++)
        acc[i][j] = __builtin_amdgcn_mfma_f32_16x16x32_bf16(af[i], wf[j],
                                                            acc[i][j], 0, 0, 0);
  }
#pragma unroll
  for (int i = 0; i < 4; i++) {
#pragma unroll
    for (int j = 0; j < 4; j++) {
      int r0 = row0 + i * 16 + kg * 4;
      int c = col0 + j * 16 + lr;
      float bv = bias[c];
#pragma unroll
      for (int r = 0; r < 4; r++) {
        float v = acc[i][j][r] + bv;
        if (RELU) v = fmaxf(v, 0.f);
        if (OUTBF)
          ((__hip_bfloat16*)Cd)[(size_t)(r0 + r) * Nn + c] = __float2bfloat16(v);
        else
          ((float*)Cd)[(size_t)(r0 + r) * Nn + c] = v;
      }
    }
  }
}

// ---------------- K3: tiny attention per (b,h), bf16 qkv in, bf16 o out -----
__global__ __launch_bounds__(256) void k_attn(
    const __hip_bfloat16* __restrict__ qkv, __hip_bfloat16* __restrict__ o) {
  int bh = blockIdx.x;
  int b = bh / HH, h = bh % HH;
  __shared__ float qs[12][64], ks[12][64], vs[12][64], sm[12][12];
  int t = threadIdx.x;
  for (int u = t; u < 768; u += 256) {
    int p = u >> 6, d = u & 63;
    size_t base = ((size_t)(b * PP + p)) * 2304 + h * 64 + d;
    qs[p][d] = bf16_val(qkv + base);
    ks[p][d] = bf16_val(qkv + base + 768);
    vs[p][d] = bf16_val(qkv + base + 1536);
  }
  __syncthreads();
  if (t < 144) {
    int i = t / 12, j = t % 12;
    float s = 0.f;
#pragma unroll
    for (int d = 0; d < 64; d++) s += qs[i][d] * ks[j][d];
    sm[i][j] = s * 0.125f;  // 1/sqrt(64)
  }
  __syncthreads();
  if (t < 12) {
    float m = -FLT_MAX;
    for (int j = 0; j < 12; j++) m = fmaxf(m, sm[t][j]);
    float e[12], sum = 0.f;
    for (int j = 0; j < 12; j++) { e[j] = expf(sm[t][j] - m); sum += e[j]; }
    float inv = 1.f / sum;
    for (int j = 0; j < 12; j++) sm[t][j] = e[j] * inv;
  }
  __syncthreads();
  for (int u = t; u < 768; u += 256) {
    int i = u >> 6, d = u & 63;
    float s = 0.f;
#pragma unroll
    for (int j = 0; j < 12; j++) s += sm[i][j] * vs[j][d];
    o[((size_t)(b * PP + i)) * DD + h * 64 + d] = __float2bfloat16(s);
  }
}

// ---------------- K5: LN2 (in-place f32) + pooling logit per row ------------
__global__ __launch_bounds__(256) void k_ln2_pool(
    float* __restrict__ x, const float* __restrict__ g,
    const float* __restrict__ be, const float* __restrict__ wp,
    const float* __restrict__ bp, float* __restrict__ raww) {
  int r = blockIdx.x, t = threadIdx.x;
  __shared__ float red[256], red2[256];
  float* row = x + (size_t)r * DD;
  float x0 = row[t], x1 = row[t + 256], x2 = row[t + 512];
  red[t] = x0 + x1 + x2;
  red2[t] = x0 * x0 + x1 * x1 + x2 * x2;
  __syncthreads();
  for (int st = 128; st > 0; st >>= 1) {
    if (t < st) { red[t] += red[t + st]; red2[t] += red2[t + st]; }
    __syncthreads();
  }
  float mean = red[0] * (1.f / DD);
  float var = red2[0] * (1.f / DD) - mean * mean;
  float rstd = rsqrtf(var + 1e-5f);
  float y0 = (x0 - mean) * rstd * g[t] + be[t];
  float y1 = (x1 - mean) * rstd * g[t + 256] + be[t + 256];
  float y2 = (x2 - mean) * rstd * g[t + 512] + be[t + 512];
  row[t] = y0; row[t + 256] = y1; row[t + 512] = y2;
  __syncthreads();
  red[t] = y0 * wp[t] + y1 * wp[t + 256] + y2 * wp[t + 512];
  __syncthreads();
  for (int st = 128; st > 0; st >>= 1) {
    if (t < st) red[t] += red[t + st];
    __syncthreads();
  }
  if (t == 0) raww[r] = red[0] + bp[0];
}

// ---------------- K6: pool softmax + weighted sum -> bf16 pfeat -------------
__global__ __launch_bounds__(256) void k_pool(
    const float* __restrict__ aout, const float* __restrict__ raww,
    const float* __restrict__ ptemp, __hip_bfloat16* __restrict__ pf) {
  int b = blockIdx.x, t = threadIdx.x;
  __shared__ float w[12];
  if (t == 0) {
    float temp = fmaxf(ptemp[0], 0.3f), inv = 1.f / temp;
    float z[12], m = -FLT_MAX;
    for (int p = 0; p < 12; p++) { z[p] = raww[b * 12 + p] * inv; m = fmaxf(m, z[p]); }
    float s = 0.f;
    for (int p = 0; p < 12; p++) { z[p] = expf(z[p] - m); s += z[p]; }
    float is = 1.f / s;
    for (int p = 0; p < 12; p++) w[p] = z[p] * is;
  }
  __syncthreads();
  for (int d = t; d < DD; d += 256) {
    float s = 0.f;
#pragma unroll
    for (int p = 0; p < 12; p++) s += aout[((size_t)(b * 12 + p)) * DD + d] * w[p];
    pf[(size_t)b * DD + d] = __float2bfloat16(s);
  }
}

// ---------------- K8a: fusion vector, normalized, -> ws ---------------------
__global__ __launch_bounds__(256) void k_fusion(
    const float* __restrict__ hidden, const float* __restrict__ pmlp,
    float* __restrict__ fus_n) {
  int b = blockIdx.x, t = threadIdx.x;
  __shared__ float red[256];
  __shared__ float rnf;
  float v[6];
#pragma unroll
  for (int j = 0; j < 6; j++) {
    int u = t + j * 256;
    v[j] = (u < 768) ? hidden[((size_t)b * NNtok) * DD + u]
                     : pmlp[(size_t)b * DD + (u - 768)];
  }
  float s = 0.f;
#pragma unroll
  for (int j = 0; j < 6; j++) s += v[j] * v[j];
  red[t] = s;
  __syncthreads();
  for (int st = 128; st > 0; st >>= 1) {
    if (t < st) red[t] += red[t + st];
    __syncthreads();
  }
  if (t == 0) rnf = rsqrtf(red[0]);
  __syncthreads();
  float r = rnf;
#pragma unroll
  for (int j = 0; j < 6; j++) fus_n[(size_t)b * 1536 + t + j * 256] = v[j] * r;
}

// ---------------- K8b: ArcFace logits, 8 classes/block ----------------------
__global__ __launch_bounds__(256) void k_arc2(
    const float* __restrict__ fus_n, const float* __restrict__ aw,
    const float* __restrict__ rn, const int* __restrict__ labels,
    float* __restrict__ out) {
  int cbase = blockIdx.x * 8, b = blockIdx.y, t = threadIdx.x;
  __shared__ float4 fs[384];
  for (int u = t; u < 384; u += 256)
    fs[u] = ((const float4*)(fus_n + (size_t)b * 1536))[u];
  __syncthreads();
  int wv = t >> 6, ln = t & 63;
  int lab = labels[b];
  const float cos_m = 0.8775825618903728f, sin_m = 0.479425538604203f;
  const float th = -0.8775825618903728f, mm = 0.2397127693021015f;
#pragma unroll
  for (int ci = 0; ci < 2; ci++) {
    int c = cbase + wv + ci * 4;
    const float4* awr = (const float4*)(aw + (size_t)c * 1536);
    float acc = 0.f;
#pragma unroll
    for (int k = 0; k < 6; k++) {
      float4 a = fs[ln + k * 64];
      float4 w = awr[ln + k * 64];
      acc += a.x * w.x + a.y * w.y + a.z * w.z + a.w * w.w;
    }
    for (int off = 32; off > 0; off >>= 1) acc += __shfl_down(acc, off);
    if (ln == 0) {
      float cosv = acc * rn[c];
      float s2 = 1.f - cosv * cosv;
      s2 = fminf(fmaxf(s2, 0.f), 1.f);
      float sinv = sqrtf(s2);
      float phi = cosv * cos_m - sinv * sin_m;
      phi = (cosv > th) ? phi : (cosv - mm);
      out[(size_t)b * CC + c] = ((c == lab) ? phi : cosv) * 30.f;
    }
  }
}

extern "C" void kernel_launch(void* const* d_in, const int* in_sizes, int n_in,
                              void* d_out, int out_size, void* d_ws, size_t ws_size,
                              hipStream_t stream) {
  const float* hidden = (const float*)d_in[0];
  const float* attns  = (const float*)d_in[1];
  const int*   labels = (const int*)d_in[2];
  const float* ln1_g  = (const float*)d_in[3];
  const float* ln1_b  = (const float*)d_in[4];
  const float* w_in   = (const float*)d_in[5];
  const float* b_in   = (const float*)d_in[6];
  const float* w_out  = (const float*)d_in[7];
  const float* b_out  = (const float*)d_in[8];
  const float* ln2_g  = (const float*)d_in[9];
  const float* ln2_b  = (const float*)d_in[10];
  const float* w_pool = (const float*)d_in[11];
  const float* b_pool = (const float*)d_in[12];
  const float* ptemp  = (const float*)d_in[13];
  const float* w_mlp  = (const float*)d_in[14];
  const float* b_mlp  = (const float*)d_in[15];
  const float* arc_w  = (const float*)d_in[16];
  float* outp = (float*)d_out;

  float* F = (float*)d_ws;
  // layout (floats; all region starts multiple of 256 -> 16B-aligned)
  float* wnr   = F;                        // 256
  float* raww  = F + 256;                  // 768
  float* reg1  = F + 1024;                 // 884736 floats: qkv_bf then aout f32
  float* pmlp  = F + 885760;               // 49152
  float* fus_n = F + 934912;               // 98304
  __hip_bfloat16* parts_bf = (__hip_bfloat16*)(F + 1033216);  // 589824 bf16 (294912 f)
  __hip_bfloat16* w_in_bf  = (__hip_bfloat16*)(F + 1328128);  // 1769472 bf16
  __hip_bfloat16* w_out_bf = (__hip_bfloat16*)(F + 2212864);  // 589824 bf16
  __hip_bfloat16* w_mlp_bf = (__hip_bfloat16*)(F + 2507776);  // 589824 bf16
  __hip_bfloat16* pfeat_bf = (__hip_bfloat16*)(F + 2802688);  // 49152 bf16
  int* sel_g = (int*)(F + 2827264);        // 768 ints
  // aliases (disjoint lifetimes):
  __hip_bfloat16* qkv_bf = (__hip_bfloat16*)reg1;  // dead after k_attn
  float* aout = reg1;                              // written by wout GEMM
  __hip_bfloat16* obuf_bf = parts_bf;              // parts dead after qkv GEMM

  k_wnorm<<<200, 64, 0, stream>>>(arc_w, wnr);
  k_cast3<<<2880, 256, 0, stream>>>(w_in, w_out, w_mlp, w_in_bf, w_out_bf, w_mlp_bf);
  k_select<<<BB, 256, 0, stream>>>(attns, sel_g);
  k_gather_ln1<<<BB * PP, 256, 0, stream>>>(hidden, sel_g, ln1_g, ln1_b, parts_bf);
  // qkv = parts @ w_in^T + b_in  (768x2304x768) -> bf16
  k_gemm_bf<2, 2, 0, 1><<<dim3(18, 6), 256, 0, stream>>>(parts_bf, w_in_bf, b_in,
                                                         (void*)qkv_bf, 2304, 768);
  k_attn<<<BB * HH, 256, 0, stream>>>(qkv_bf, obuf_bf);
  // attn_out = o @ w_out^T + b_out (768x768x768) -> f32
  k_gemm_bf<2, 2, 0, 0><<<dim3(6, 6), 256, 0, stream>>>(obuf_bf, w_out_bf, b_out,
                                                        (void*)aout, 768, 768);
  k_ln2_pool<<<BB * PP, 256, 0, stream>>>(aout, ln2_g, ln2_b, w_pool, b_pool, raww);
  k_pool<<<BB, 256, 0, stream>>>(aout, raww, ptemp, pfeat_bf);
  // pmlp = relu(pfeat @ w_mlp^T + b_mlp) (64x768x768) -> f32
  k_gemm_bf<1, 1, 1, 0><<<dim3(12, 1), 64, 0, stream>>>(pfeat_bf, w_mlp_bf, b_mlp,
                                                        (void*)pmlp, 768, 768);
  k_fusion<<<BB, 256, 0, stream>>>(hidden, pmlp, fus_n);
  k_arc2<<<dim3(25, BB), 256, 0, stream>>>(fus_n, arc_w, wnr, labels, outp);
}

// Round 4
// 105.400 us; speedup vs baseline: 5.0148x; 1.0811x over previous
//
#include <hip/hip_runtime.h>
#include <hip/hip_bf16.h>
#include <float.h>
#include <math.h>

#define BB 64
#define NNtok 197
#define DD 768
#define HH 12
#define PP 12
#define CC 200
#define NPATCH 196

typedef short bf16x8 __attribute__((ext_vector_type(8)));
typedef float f32x4 __attribute__((ext_vector_type(4)));

__device__ __forceinline__ unsigned short bf16_bits(float x) {
  __hip_bfloat16 h = __float2bfloat16(x);
  return *reinterpret_cast<unsigned short*>(&h);
}
__device__ __forceinline__ float bf16u_val(unsigned short us) {
  union { unsigned int u; float f; } cv;
  cv.u = ((unsigned int)us) << 16;
  return cv.f;
}
__device__ __forceinline__ float bf16_val(const __hip_bfloat16* p) {
  return __bfloat162float(*p);
}

// ---------------- K1: [blocks 0..63] select+top12+gather+LN1 ; [64..] casts --
__global__ __launch_bounds__(256) void k_front(
    const float* __restrict__ hidden, const float* __restrict__ attns,
    const float* __restrict__ g, const float* __restrict__ be,
    const float* __restrict__ w1, const float* __restrict__ w2,
    const float* __restrict__ w3, __hip_bfloat16* __restrict__ o1,
    __hip_bfloat16* __restrict__ o2, __hip_bfloat16* __restrict__ o3,
    __hip_bfloat16* __restrict__ parts) {
  int t = threadIdx.x;
  int bi = blockIdx.x;
  if (bi >= 64) {
    // weight casts: w_in (442368 f4), w_out (147456 f4), w_mlp (147456 f4)
    int i = (bi - 64) * 256 + t;
    const float* src; __hip_bfloat16* dst; int off;
    if (i < 442368) { src = w1; dst = o1; off = i; }
    else if (i < 589824) { src = w2; dst = o2; off = i - 442368; }
    else { src = w3; dst = o3; off = i - 589824; }
    float4 v = ((const float4*)src)[off];
    union { unsigned short u[4]; ushort4 v4; } p;
    p.u[0] = bf16_bits(v.x); p.u[1] = bf16_bits(v.y);
    p.u[2] = bf16_bits(v.z); p.u[3] = bf16_bits(v.w);
    ((ushort4*)dst)[off] = p.v4;
    return;
  }
  int b = bi;
  __shared__ float sc[256];
  __shared__ int sel_s[PP];
  // scores: mean over heads (/12) then over layers (/4), matching ref order
  float acc = -FLT_MAX;
  if (t < NPATCH) {
    acc = 0.f;
#pragma unroll
    for (int l = 0; l < 4; l++) {
      float part = 0.f;
#pragma unroll
      for (int h = 0; h < HH; h++) {
        size_t base = (size_t)((l * BB + b) * HH + h) * ((size_t)NNtok * NNtok);
        part += attns[base + 1 + t];
      }
      acc += part * (1.f / 12.f);
    }
    acc *= 0.25f;
  }
  sc[t] = acc;
  __syncthreads();
  if (t < 64) {
    float v[4]; int idx[4];
#pragma unroll
    for (int j = 0; j < 4; j++) { idx[j] = t + j * 64; v[j] = sc[idx[j]]; }
    for (int it = 0; it < PP; ++it) {
      float bv = v[0]; int bidx = idx[0];
#pragma unroll
      for (int j = 1; j < 4; j++)
        if (v[j] > bv || (v[j] == bv && idx[j] < bidx)) { bv = v[j]; bidx = idx[j]; }
      float cv = bv; int ci = bidx;
#pragma unroll
      for (int off = 32; off > 0; off >>= 1) {
        float ov = __shfl_xor(cv, off); int oi = __shfl_xor(ci, off);
        if (ov > cv || (ov == cv && oi < ci)) { cv = ov; ci = oi; }
      }
      if (t == 0) sel_s[it] = ci;
#pragma unroll
      for (int j = 0; j < 4; j++)
        if (idx[j] == ci) v[j] = -FLT_MAX;
    }
  }
  __syncthreads();
  // gather + LN1, barrier-free: wave wv owns rows wv*3..wv*3+2
  int wv = t >> 6, ln = t & 63;
#pragma unroll
  for (int q = 0; q < 3; q++) {
    int i = wv * 3 + q;
    const float* row = hidden + ((size_t)b * NNtok + 1 + sel_s[i]) * DD;
    float x[12], s1 = 0.f, s2 = 0.f;
#pragma unroll
    for (int k = 0; k < 12; k++) {
      x[k] = row[ln + 64 * k];
      s1 += x[k]; s2 += x[k] * x[k];
    }
#pragma unroll
    for (int off = 32; off > 0; off >>= 1) {
      s1 += __shfl_xor(s1, off); s2 += __shfl_xor(s2, off);
    }
    float m = s1 * (1.f / DD);
    float rstd = rsqrtf(s2 * (1.f / DD) - m * m + 1e-5f);
    __hip_bfloat16* out = parts + ((size_t)b * PP + i) * DD;
#pragma unroll
    for (int k = 0; k < 12; k++) {
      int d = ln + 64 * k;
      out[d] = __float2bfloat16((x[k] - m) * rstd * g[d] + be[d]);
    }
  }
}

// ---------------- MFMA GEMM: C = A(MxK) @ W(NxK)^T + bias -------------------
// wave tile (MI*16)x(NJ*16); block = WM x WN waves.
template <int MI, int NJ, int WM, int WN, int RELU, int OUTBF>
__global__ __launch_bounds__(WM * WN * 64) void k_gemm_bf(
    const __hip_bfloat16* __restrict__ A, const __hip_bfloat16* __restrict__ W,
    const float* __restrict__ bias, void* __restrict__ Cd, int Nn, int Kk) {
  int t = threadIdx.x;
  int wave = t >> 6, lane = t & 63;
  int wm = wave / WN, wn = wave % WN;
  int row0 = blockIdx.y * (WM * MI * 16) + wm * MI * 16;
  int col0 = blockIdx.x * (WN * NJ * 16) + wn * NJ * 16;
  int lr = lane & 15;   // row (A) / col (W) within 16
  int kg = lane >> 4;   // k-group of 8
  f32x4 acc[MI][NJ];
#pragma unroll
  for (int i = 0; i < MI; i++)
#pragma unroll
    for (int j = 0; j < NJ; j++) {
      acc[i][j][0] = 0.f; acc[i][j][1] = 0.f;
      acc[i][j][2] = 0.f; acc[i][j][3] = 0.f;
    }
  const __hip_bfloat16* Ab = A + (size_t)(row0 + lr) * Kk + kg * 8;
  const __hip_bfloat16* Wb = W + (size_t)(col0 + lr) * Kk + kg * 8;
  for (int k0 = 0; k0 < Kk; k0 += 32) {
    bf16x8 af[MI], wf[NJ];
#pragma unroll
    for (int i = 0; i < MI; i++)
      af[i] = *(const bf16x8*)(Ab + (size_t)i * 16 * Kk + k0);
#pragma unroll
    for (int j = 0; j < NJ; j++)
      wf[j] = *(const bf16x8*)(Wb + (size_t)j * 16 * Kk + k0);
#pragma unroll
    for (int i = 0; i < MI; i++)
#pragma unroll
      for (int j = 0; j < NJ; j++)
        acc[i][j] = __builtin_amdgcn_mfma_f32_16x16x32_bf16(af[i], wf[j],
                                                            acc[i][j], 0, 0, 0);
  }
#pragma unroll
  for (int i = 0; i < MI; i++) {
#pragma unroll
    for (int j = 0; j < NJ; j++) {
      int r0 = row0 + i * 16 + kg * 4;
      int c = col0 + j * 16 + lr;
      float bv = bias[c];
#pragma unroll
      for (int r = 0; r < 4; r++) {
        float v = acc[i][j][r] + bv;
        if (RELU) v = fmaxf(v, 0.f);
        if (OUTBF)
          ((__hip_bfloat16*)Cd)[(size_t)(r0 + r) * Nn + c] = __float2bfloat16(v);
        else
          ((float*)Cd)[(size_t)(r0 + r) * Nn + c] = v;
      }
    }
  }
}

// ---------------- K3: tiny attention per (b,h), bf16 qkv in, bf16 o out -----
__global__ __launch_bounds__(256) void k_attn(
    const __hip_bfloat16* __restrict__ qkv, __hip_bfloat16* __restrict__ o) {
  int bh = blockIdx.x;
  int b = bh / HH, h = bh % HH;
  __shared__ float qs[12][64], ks[12][64], vs[12][64], sm[12][12];
  int t = threadIdx.x;
  for (int u = t; u < 768; u += 256) {
    int p = u >> 6, d = u & 63;
    size_t base = ((size_t)(b * PP + p)) * 2304 + h * 64 + d;
    qs[p][d] = bf16_val(qkv + base);
    ks[p][d] = bf16_val(qkv + base + 768);
    vs[p][d] = bf16_val(qkv + base + 1536);
  }
  __syncthreads();
  if (t < 144) {
    int i = t / 12, j = t % 12;
    float s = 0.f;
#pragma unroll
    for (int d = 0; d < 64; d++) s += qs[i][d] * ks[j][d];
    sm[i][j] = s * 0.125f;  // 1/sqrt(64)
  }
  __syncthreads();
  if (t < 12) {
    float m = -FLT_MAX;
    for (int j = 0; j < 12; j++) m = fmaxf(m, sm[t][j]);
    float e[12], sum = 0.f;
    for (int j = 0; j < 12; j++) { e[j] = expf(sm[t][j] - m); sum += e[j]; }
    float inv = 1.f / sum;
    for (int j = 0; j < 12; j++) sm[t][j] = e[j] * inv;
  }
  __syncthreads();
  for (int u = t; u < 768; u += 256) {
    int i = u >> 6, d = u & 63;
    float s = 0.f;
#pragma unroll
    for (int j = 0; j < 12; j++) s += sm[i][j] * vs[j][d];
    o[((size_t)(b * PP + i)) * DD + h * 64 + d] = __float2bfloat16(s);
  }
}

// ---------------- K5: LN2 + pool softmax + weighted sum + MLP + ReLU --------
__global__ __launch_bounds__(256) void k_head(
    const float* __restrict__ aout, const float* __restrict__ g,
    const float* __restrict__ be, const float* __restrict__ wp,
    const float* __restrict__ bp, const float* __restrict__ ptemp,
    const __hip_bfloat16* __restrict__ wmlp, const float* __restrict__ bmlp,
    float* __restrict__ pmlp) {
  int b = blockIdx.x, t = threadIdx.x, wv = t >> 6, ln = t & 63;
  __shared__ float ybuf[12][768];
  __shared__ float raww_s[12];
  __shared__ float pfeat_s[768];
#pragma unroll
  for (int q = 0; q < 3; q++) {
    int r = wv * 3 + q;
    const float* row = aout + ((size_t)(b * PP + r)) * DD;
    float x[12], s1 = 0.f, s2 = 0.f;
#pragma unroll
    for (int k = 0; k < 12; k++) {
      x[k] = row[ln + 64 * k];
      s1 += x[k]; s2 += x[k] * x[k];
    }
#pragma unroll
    for (int off = 32; off > 0; off >>= 1) {
      s1 += __shfl_xor(s1, off); s2 += __shfl_xor(s2, off);
    }
    float m = s1 * (1.f / DD);
    float rstd = rsqrtf(s2 * (1.f / DD) - m * m + 1e-5f);
    float pl = 0.f;
#pragma unroll
    for (int k = 0; k < 12; k++) {
      int d = ln + 64 * k;
      float y = (x[k] - m) * rstd * g[d] + be[d];
      ybuf[r][d] = y;
      pl += y * wp[d];
    }
#pragma unroll
    for (int off = 32; off > 0; off >>= 1) pl += __shfl_xor(pl, off);
    if (ln == 0) raww_s[r] = pl + bp[0];
  }
  __syncthreads();
  // pool softmax (redundant per thread; all values identical)
  float wts[12];
  {
    float inv = 1.f / fmaxf(ptemp[0], 0.3f);
    float z[12], mx = -FLT_MAX;
#pragma unroll
    for (int p = 0; p < 12; p++) { z[p] = raww_s[p] * inv; mx = fmaxf(mx, z[p]); }
    float s = 0.f;
#pragma unroll
    for (int p = 0; p < 12; p++) { z[p] = expf(z[p] - mx); s += z[p]; }
    float is = 1.f / s;
#pragma unroll
    for (int p = 0; p < 12; p++) wts[p] = z[p] * is;
  }
  for (int d = t; d < DD; d += 256) {
    float s = 0.f;
#pragma unroll
    for (int p = 0; p < 12; p++) s += ybuf[p][d] * wts[p];
    pfeat_s[d] = s;
  }
  __syncthreads();
  // MLP GEMV: pmlp[j] = relu(b_mlp[j] + sum_d pfeat[d]*wmlp[j][d])
  for (int j = t; j < DD; j += 256) {
    const bf16x8* wr = (const bf16x8*)(wmlp + (size_t)j * DD);
    float acc2 = bmlp[j];
    for (int k = 0; k < 96; k++) {
      bf16x8 w8 = wr[k];
      const float* pf = &pfeat_s[k * 8];
#pragma unroll
      for (int e = 0; e < 8; e++)
        acc2 += pf[e] * bf16u_val((unsigned short)w8[e]);
    }
    pmlp[(size_t)b * DD + j] = fmaxf(acc2, 0.f);
  }
}

// ---------------- K8: fusion + normalize + arc_w norms + ArcFace ------------
__global__ __launch_bounds__(256) void k_arc3(
    const float* __restrict__ hidden, const float* __restrict__ pmlp,
    const float* __restrict__ aw, const int* __restrict__ labels,
    float* __restrict__ out) {
  int b = blockIdx.y, t = threadIdx.x;
  __shared__ float4 fs[384];
  __shared__ float a4[4];
  const float4* cls4 = (const float4*)(hidden + (size_t)b * NNtok * DD);
  const float4* pm4 = (const float4*)(pmlp + (size_t)b * DD);
  for (int u = t; u < 384; u += 256) fs[u] = (u < 192) ? cls4[u] : pm4[u - 192];
  __syncthreads();
  float s = 0.f;
  for (int u = t; u < 384; u += 256) {
    float4 v = fs[u];
    s += v.x * v.x + v.y * v.y + v.z * v.z + v.w * v.w;
  }
#pragma unroll
  for (int off = 32; off > 0; off >>= 1) s += __shfl_xor(s, off);
  if ((t & 63) == 0) a4[t >> 6] = s;
  __syncthreads();
  float rnf = rsqrtf(a4[0] + a4[1] + a4[2] + a4[3]);
  int wv = t >> 6, ln = t & 63;
  int lab = labels[b];
  const float cos_m = 0.8775825618903728f, sin_m = 0.479425538604203f;
  const float th = -0.8775825618903728f, mm = 0.2397127693021015f;
#pragma unroll
  for (int ci = 0; ci < 2; ci++) {
    int c = blockIdx.x * 8 + wv + ci * 4;
    const float4* wr = (const float4*)(aw + (size_t)c * 1536);
    float acc = 0.f, nw = 0.f;
#pragma unroll
    for (int k = 0; k < 6; k++) {
      float4 a = fs[ln + 64 * k];
      float4 w = wr[ln + 64 * k];
      acc += a.x * w.x + a.y * w.y + a.z * w.z + a.w * w.w;
      nw += w.x * w.x + w.y * w.y + w.z * w.z + w.w * w.w;
    }
#pragma unroll
    for (int off = 32; off > 0; off >>= 1) {
      acc += __shfl_xor(acc, off); nw += __shfl_xor(nw, off);
    }
    if (ln == 0) {
      float cosv = acc * rsqrtf(nw) * rnf;
      float s2 = 1.f - cosv * cosv;
      s2 = fminf(fmaxf(s2, 0.f), 1.f);
      float sinv = sqrtf(s2);
      float phi = cosv * cos_m - sinv * sin_m;
      phi = (cosv > th) ? phi : (cosv - mm);
      out[(size_t)b * CC + c] = ((c == lab) ? phi : cosv) * 30.f;
    }
  }
}

extern "C" void kernel_launch(void* const* d_in, const int* in_sizes, int n_in,
                              void* d_out, int out_size, void* d_ws, size_t ws_size,
                              hipStream_t stream) {
  const float* hidden = (const float*)d_in[0];
  const float* attns  = (const float*)d_in[1];
  const int*   labels = (const int*)d_in[2];
  const float* ln1_g  = (const float*)d_in[3];
  const float* ln1_b  = (const float*)d_in[4];
  const float* w_in   = (const float*)d_in[5];
  const float* b_in   = (const float*)d_in[6];
  const float* w_out  = (const float*)d_in[7];
  const float* b_out  = (const float*)d_in[8];
  const float* ln2_g  = (const float*)d_in[9];
  const float* ln2_b  = (const float*)d_in[10];
  const float* w_pool = (const float*)d_in[11];
  const float* b_pool = (const float*)d_in[12];
  const float* ptemp  = (const float*)d_in[13];
  const float* w_mlp  = (const float*)d_in[14];
  const float* b_mlp  = (const float*)d_in[15];
  const float* arc_w  = (const float*)d_in[16];
  float* outp = (float*)d_out;

  float* F = (float*)d_ws;
  // layout (float units)
  float* reg1 = F;                                            // 884736 (qkv_bf | aout)
  float* pmlp = F + 884736;                                   // 49152
  __hip_bfloat16* parts_bf = (__hip_bfloat16*)(F + 933888);   // 589824 bf16 (294912 f)
  __hip_bfloat16* w_in_bf  = (__hip_bfloat16*)(F + 1228800);  // 1769472 bf16 (884736 f)
  __hip_bfloat16* w_out_bf = (__hip_bfloat16*)(F + 2113536);  // 589824 bf16 (294912 f)
  __hip_bfloat16* w_mlp_bf = (__hip_bfloat16*)(F + 2408448);  // 589824 bf16 (294912 f)
  // aliases (disjoint lifetimes):
  __hip_bfloat16* qkv_bf = (__hip_bfloat16*)reg1;  // dead after k_attn
  float* aout = reg1;                              // written by wout GEMM
  __hip_bfloat16* obuf_bf = parts_bf;              // parts dead after qkv GEMM

  // 1: selection+LN1 (blocks 0..63) + weight casts (blocks 64..2943)
  k_front<<<2944, 256, 0, stream>>>(hidden, attns, ln1_g, ln1_b,
                                    w_in, w_out, w_mlp,
                                    w_in_bf, w_out_bf, w_mlp_bf, parts_bf);
  // 2: qkv = parts @ w_in^T + b_in (768x2304x768) -> bf16. block 128x64, grid 36x6
  k_gemm_bf<2, 4, 4, 1, 0, 1><<<dim3(36, 6), 256, 0, stream>>>(
      parts_bf, w_in_bf, b_in, (void*)qkv_bf, 2304, 768);
  // 3: attention
  k_attn<<<BB * HH, 256, 0, stream>>>(qkv_bf, obuf_bf);
  // 4: attn_out = o @ w_out^T + b_out (768x768x768) -> f32. block 64x64, grid 12x12
  k_gemm_bf<2, 2, 2, 2, 0, 0><<<dim3(12, 12), 256, 0, stream>>>(
      obuf_bf, w_out_bf, b_out, (void*)aout, 768, 768);
  // 5: LN2 + pool + MLP
  k_head<<<BB, 256, 0, stream>>>(aout, ln2_g, ln2_b, w_pool, b_pool, ptemp,
                                 w_mlp_bf, b_mlp, pmlp);
  // 6: fusion + ArcFace
  k_arc3<<<dim3(25, BB), 256, 0, stream>>>(hidden, pmlp, arc_w, labels, outp);
}